// Round 1
// baseline (168.030 us; speedup 1.0000x reference)
//
#include <hip/hip_runtime.h>

#define N_NODES_C 8192
#define MAX_PATH_C 5
#define EDGE_DIM_C 32

// Pass 1: tag each output cell with (max path index + 1) -> numpy last-write-wins.
__global__ void __launch_bounds__(256) ee_pass1_winner(
    const int* __restrict__ src, const int* __restrict__ dst,
    unsigned int* __restrict__ outw, int P)
{
    int p = blockIdx.x * blockDim.x + threadIdx.x;
    if (p >= P) return;
    long long cell = (long long)src[p] * N_NODES_C + (long long)dst[p];
    atomicMax(outw + cell, (unsigned int)(p + 1));
}

// Pass 2: winner path replaces its tag with the encoded value.
__global__ void __launch_bounds__(256) ee_pass2_enc(
    const float* __restrict__ edge_attr,
    const float* __restrict__ edge_weights,
    const int* __restrict__ paths,
    const int* __restrict__ path_lens,
    const int* __restrict__ src, const int* __restrict__ dst,
    float* __restrict__ out, int P)
{
    __shared__ __align__(16) float w[MAX_PATH_C * EDGE_DIM_C];
    for (int i = threadIdx.x; i < MAX_PATH_C * EDGE_DIM_C; i += blockDim.x)
        w[i] = edge_weights[i];
    __syncthreads();

    int p = blockIdx.x * blockDim.x + threadIdx.x;
    if (p >= P) return;

    long long cell = (long long)src[p] * N_NODES_C + (long long)dst[p];
    const unsigned int* outw = (const unsigned int*)out;
    if (outw[cell] != (unsigned int)(p + 1)) return;  // not the last writer

    int len = (int)path_lens[p];
    float s = 0.0f;
    #pragma unroll
    for (int l = 0; l < MAX_PATH_C; ++l) {
        if (l < len) {
            long long e = (long long)paths[p * MAX_PATH_C + l];
            const float4* __restrict__ row =
                (const float4*)(edge_attr + e * EDGE_DIM_C);
            const float4* wr = (const float4*)(w + l * EDGE_DIM_C);
            float acc = 0.0f;
            #pragma unroll
            for (int j = 0; j < EDGE_DIM_C / 4; ++j) {
                float4 a = row[j];
                float4 b = wr[j];
                acc += a.x * b.x + a.y * b.y + a.z * b.z + a.w * b.w;
            }
            s += acc;
        }
    }
    float enc = (len > 0) ? s / (float)len : 0.0f;
    if (isnan(enc)) enc = 0.0f;  // nan_to_num
    out[cell] = enc;
}

extern "C" void kernel_launch(void* const* d_in, const int* in_sizes, int n_in,
                              void* d_out, int out_size, void* d_ws, size_t ws_size,
                              hipStream_t stream)
{
    // inputs: 0:x(f32) 1:edge_attr(f32) 2:edge_weights(f32)
    //         3:paths(int) 4:path_lens(int) 5:src(int) 6:dst(int)
    const float* edge_attr    = (const float*)d_in[1];
    const float* edge_weights = (const float*)d_in[2];
    const int*   paths        = (const int*)d_in[3];
    const int*   path_lens    = (const int*)d_in[4];
    const int*   src          = (const int*)d_in[5];
    const int*   dst          = (const int*)d_in[6];
    float* out = (float*)d_out;
    const int P = in_sizes[4];

    hipMemsetAsync(d_out, 0, (size_t)out_size * sizeof(float), stream);

    const int threads = 256;
    const int blocks = (P + threads - 1) / threads;
    ee_pass1_winner<<<blocks, threads, 0, stream>>>(
        src, dst, (unsigned int*)out, P);
    ee_pass2_enc<<<blocks, threads, 0, stream>>>(
        edge_attr, edge_weights, paths, path_lens, src, dst, out, P);
}